// Round 17
// baseline (228.875 us; speedup 1.0000x reference)
//
#include <hip/hip_runtime.h>
#include <math.h>

#define N_NODES   500000
#define N_EDGES   16000000
#define EPS       1e-6f

#define NBINS         256      // bin = dst >> 11  (2048 nodes per bin)
#define NODES_PER_BIN 2048
#define CHUNK         4096     // edges per scatter block
#define NBLK_A        3907     // ceil(16e6 / 4096)
#define SPLIT         8        // reduce splits per bin
#define BPB           489      // ceil(NBLK_A / SPLIT), <= 512

typedef unsigned long long u64;
typedef unsigned int u32;
typedef unsigned short u16;
typedef u32 v4u __attribute__((ext_vector_type(4)));

// u32 record layout: [0:11) lid = dst & 2047, [11:30) srcid (< 2^19), [30:32) spare.

// ---- Kernel 1: pure integer counting sort of edges by dst-bin ----
__global__ void __launch_bounds__(512) scatter_kernel(
    const int* __restrict__ src, const int* __restrict__ dst,
    u32* __restrict__ recbuf, u32* __restrict__ inclbuf)
{
    __shared__ u32 stage[CHUNK];       // 16 KB
    __shared__ u16 perm[CHUNK];        // 8 KB
    __shared__ u32 incl[NBINS];        // 1 KB
    __shared__ u32 wsum[4];

    int t = threadIdx.x, b = blockIdx.x;
    int lane = t & 63, wid = t >> 6;
    if (t < NBINS) incl[t] = 0;
    __syncthreads();

    const v4u* src4 = reinterpret_cast<const v4u*>(src);
    const v4u* dst4 = reinterpret_cast<const v4u*>(dst);
    int base4 = b * (CHUNK / 4);

    u32 rb[8];                         // bin(8) << 13 | rank(13); ~0u = invalid
    #pragma unroll
    for (int i = 0; i < 2; ++i) {
        int e4 = base4 + t + i * 512;
        #pragma unroll
        for (int j = 0; j < 4; ++j) rb[i * 4 + j] = 0xFFFFFFFFu;
        if (e4 * 4 < N_EDGES) {
            v4u s4 = __builtin_nontemporal_load(src4 + e4);
            v4u d4 = __builtin_nontemporal_load(dst4 + e4);
            #pragma unroll
            for (int j = 0; j < 4; ++j) {
                u32 s_ = (u32)min(max((int)s4[j], 0), N_NODES - 1);
                u32 d_ = (u32)min(max((int)d4[j], 0), N_NODES - 1);
                u32 rc = (s_ << 11) | (d_ & (NODES_PER_BIN - 1));
                int k = i * 4 + j;
                stage[t + k * 512] = rc;
                u32 bin = d_ >> 11;
                u32 r = atomicAdd(&incl[bin], 1u);
                rb[k] = (bin << 13) | r;
            }
        }
    }
    __syncthreads();

    u32 v = 0;
    if (t < NBINS) {
        v = incl[t];
        #pragma unroll
        for (int off = 1; off < 64; off <<= 1) {
            u32 u_ = __shfl_up(v, off, 64);
            if (lane >= off) v += u_;
        }
        if (lane == 63) wsum[wid] = v;
    }
    __syncthreads();
    if (t < NBINS) {
        u32 pre = 0;
        #pragma unroll
        for (int w2 = 0; w2 < 4; ++w2)
            pre += (w2 < wid) ? wsum[w2] : 0;
        v += pre;
        incl[t] = v;
        __builtin_nontemporal_store(v, inclbuf + (size_t)b * NBINS + t);
    }
    __syncthreads();

    #pragma unroll
    for (int k = 0; k < 8; ++k) {
        if (rb[k] != 0xFFFFFFFFu) {
            u32 bin = rb[k] >> 13;
            u32 r   = rb[k] & 8191u;
            u32 excl = bin ? incl[bin - 1] : 0;
            perm[excl + r] = (u16)(t + k * 512);
        }
    }
    __syncthreads();

    v4u* out4 = reinterpret_cast<v4u*>(recbuf + (size_t)b * CHUNK);
    #pragma unroll
    for (int i = 0; i < 2; ++i) {
        int j4 = t + i * 512;
        v4u o;
        o[0] = stage[perm[j4 * 4 + 0] & (CHUNK - 1)];
        o[1] = stage[perm[j4 * 4 + 1] & (CHUNK - 1)];
        o[2] = stage[perm[j4 * 4 + 2] & (CHUNK - 1)];
        o[3] = stage[perm[j4 * 4 + 3] & (CHUNK - 1)];
        __builtin_nontemporal_store(o, out4 + j4);
    }
}

// ---- Kernel 2: split-K decode + accumulate, 4-wide batch for MLP ----
__global__ void __launch_bounds__(512) reduce_kernel(
    const u32* __restrict__ recbuf, const u32* __restrict__ inclbuf,
    const float* __restrict__ pos, u64* __restrict__ partial)
{
    __shared__ u64 acc[NODES_PER_BIN];   // 16 KB
    __shared__ u32 pref[512];            // inclusive prefix of run lengths
    __shared__ u32 rstart[512];          // global record index of each run start
    __shared__ u32 wsum[8];

    int t = threadIdx.x;
    int k = blockIdx.x / SPLIT;
    int s = blockIdx.x % SPLIT;
    int lane = t & 63, wid = t >> 6;
    #pragma unroll
    for (int i = 0; i < 4; ++i) acc[t + i * 512] = 0;

    // one-time directory load
    int b = s * BPB + t;
    u32 len = 0, st = 0;
    if (t < BPB && b < NBLK_A) {
        const u32* ib = inclbuf + (size_t)b * NBINS;
        u32 hi = ib[k];
        u32 lo = k ? ib[k - 1] : 0;
        len = hi - lo;
        st = (u32)b * CHUNK + lo;
    }
    rstart[t] = st;

    u32 v = len;
    #pragma unroll
    for (int off = 1; off < 64; off <<= 1) {
        u32 u_ = __shfl_up(v, off, 64);
        if (lane >= off) v += u_;
    }
    if (lane == 63) wsum[wid] = v;
    __syncthreads();
    u32 pre = 0;
    #pragma unroll
    for (int w2 = 0; w2 < 8; ++w2)
        pre += (w2 < wid) ? wsum[w2] : 0;
    v += pre;
    pref[t] = v;
    __syncthreads();
    u32 T = pref[511];

    const float2* pos2 = reinterpret_cast<const float2*>(pos);
    int nodebase = k * NODES_PER_BIN;

    for (u32 idx0 = (u32)t * 4; idx0 < T; idx0 += 2048) {
        // one binary search for the batch head; forward-advance for the rest
        u32 r0 = 0, hi_ = 511;
        #pragma unroll
        for (int it = 0; it < 9; ++it) {
            u32 mid = (r0 + hi_) >> 1;
            if (idx0 < pref[mid]) hi_ = mid; else r0 = mid + 1;
        }

        u32 rc0 = 0, rc1 = 0, rc2 = 0, rc3 = 0;
        u32 n = min(4u, T - idx0);
        u32 r = r0;
        // record addresses (runs avg ~16 long: the while-advance is rare)
        u32 base = r ? pref[r - 1] : 0;
        rc0 = recbuf[rstart[r] + (idx0 - base)];
        if (n > 1) {
            while (pref[r] <= idx0 + 1) ++r;
            base = r ? pref[r - 1] : 0;
            rc1 = recbuf[rstart[r] + (idx0 + 1 - base)];
        }
        if (n > 2) {
            while (pref[r] <= idx0 + 2) ++r;
            base = r ? pref[r - 1] : 0;
            rc2 = recbuf[rstart[r] + (idx0 + 2 - base)];
        }
        if (n > 3) {
            while (pref[r] <= idx0 + 3) ++r;
            base = r ? pref[r - 1] : 0;
            rc3 = recbuf[rstart[r] + (idx0 + 3 - base)];
        }

        // issue all pos gathers (independent -> in flight together)
        u32 lid0 = rc0 & (NODES_PER_BIN - 1), sx0 = rc0 >> 11;
        u32 lid1 = rc1 & (NODES_PER_BIN - 1), sx1 = rc1 >> 11;
        u32 lid2 = rc2 & (NODES_PER_BIN - 1), sx2 = rc2 >> 11;
        u32 lid3 = rc3 & (NODES_PER_BIN - 1), sx3 = rc3 >> 11;
        float2 ps0 = pos2[sx0];
        float2 ps1 = (n > 1) ? pos2[sx1] : ps0;
        float2 ps2 = (n > 2) ? pos2[sx2] : ps0;
        float2 ps3 = (n > 3) ? pos2[sx3] : ps0;
        float2 pd0 = pos2[nodebase + lid0];
        float2 pd1 = pos2[nodebase + lid1];
        float2 pd2 = pos2[nodebase + lid2];
        float2 pd3 = pos2[nodebase + lid3];

        #pragma unroll
        for (int i = 0; i < 4; ++i) {
            if (i >= (int)n) break;
            float2 ps = (i == 0) ? ps0 : (i == 1) ? ps1 : (i == 2) ? ps2 : ps3;
            float2 pd = (i == 0) ? pd0 : (i == 1) ? pd1 : (i == 2) ? pd2 : pd3;
            u32 lid  = (i == 0) ? lid0 : (i == 1) ? lid1 : (i == 2) ? lid2 : lid3;
            float dx = ps.x - pd.x;
            float dy = ps.y - pd.y;
            float nrm = sqrtf(dx * dx + dy * dy) + EPS;
            float inv = 1.0f / nrm;
            float ux = dx * inv, uy = dy * inv;
            float cdx = fminf(fmaxf(dx, -12.0f), 12.0f);
            float cdy = fminf(fmaxf(dy, -12.0f), 12.0f);
            u32 qdx = (u32)__float2int_rn((cdx + 12.0f) * 16.0f);
            u32 qdy = (u32)__float2int_rn((cdy + 12.0f) * 16.0f);
            u32 qux = (u32)__float2int_rn((ux + 1.0f) * 16.0f);
            u32 quy = (u32)__float2int_rn((uy + 1.0f) * 16.0f);
            u64 w = (u64)qdx | ((u64)qdy << 16) | ((u64)qux << 32)
                  | ((u64)quy << 44) | (1ULL << 56);
            atomicAdd(&acc[lid], w);
        }
    }
    __syncthreads();

    u64* dstp = partial + ((size_t)k * SPLIT + s) * NODES_PER_BIN;
    #pragma unroll
    for (int i = 0; i < 4; ++i) {
        int idx = t + i * 512;
        __builtin_nontemporal_store(acc[idx], dstp + idx);
    }
}

// ---- Kernel 3: combine partials + finalize ----
__global__ void __launch_bounds__(512) combine_kernel(
    const u64* __restrict__ partial, const float* __restrict__ pos,
    float* __restrict__ out)
{
    int i = blockIdx.x * 512 + threadIdx.x;
    if (i >= N_NODES) return;
    int k = i >> 11;
    int lid = i & (NODES_PER_BIN - 1);
    const u64* p = partial + (size_t)k * SPLIT * NODES_PER_BIN + lid;
    u64 w = 0;
    #pragma unroll
    for (int s = 0; s < SPLIT; ++s)
        w += __builtin_nontemporal_load(p + (size_t)s * NODES_PER_BIN);

    float cnt = (float)(u32)(w >> 56);
    float sdx = (float)(u32)(w & 0xFFFFULL)         * (1.0f/16.0f) - 12.0f * cnt;
    float sdy = (float)(u32)((w >> 16) & 0xFFFFULL) * (1.0f/16.0f) - 12.0f * cnt;
    float sux = (float)(u32)((w >> 32) & 0xFFFULL)  * (1.0f/16.0f) -  1.0f * cnt;
    float suy = (float)(u32)((w >> 44) & 0xFFFULL)  * (1.0f/16.0f) -  1.0f * cnt;
    float invc = 1.0f / fmaxf(cnt, 1.0f);
    float2 pp = reinterpret_cast<const float2*>(pos)[i];
    float* row = out + (size_t)i * 6;
    row[0] = sdx * invc;
    row[1] = sdy * invc;
    row[2] = sux * invc;
    row[3] = suy * invc;
    row[4] = pp.x;
    row[5] = pp.y;
}

// ---------------- Fallback (round-3 single-atomic path) ----------------
__global__ void __launch_bounds__(256) edge_scatter_kernel(
    const int* __restrict__ src, const int* __restrict__ dst,
    const float* __restrict__ pos, u64* __restrict__ acc)
{
    int e = blockIdx.x * blockDim.x + threadIdx.x;
    if (e >= N_EDGES) return;
    int s = src[e];
    int d = dst[e];
    if ((unsigned)s >= (unsigned)N_NODES || (unsigned)d >= (unsigned)N_NODES) return;
    float2 ps = reinterpret_cast<const float2*>(pos)[s];
    float2 pd = reinterpret_cast<const float2*>(pos)[d];
    float dx = ps.x - pd.x, dy = ps.y - pd.y;
    float nrm = sqrtf(dx*dx + dy*dy) + EPS;
    float inv = 1.0f / nrm;
    float ux = dx * inv, uy = dy * inv;
    float cdx = fminf(fmaxf(dx, -12.0f), 12.0f);
    float cdy = fminf(fmaxf(dy, -12.0f), 12.0f);
    u64 qdx = (u64)(u32)__float2int_rn((cdx + 12.0f) * 16.0f);
    u64 qdy = (u64)(u32)__float2int_rn((cdy + 12.0f) * 16.0f);
    u64 qux = (u64)(u32)__float2int_rn((ux + 1.0f) * 16.0f);
    u64 quy = (u64)(u32)__float2int_rn((uy + 1.0f) * 16.0f);
    u64 w = qdx | (qdy << 16) | (qux << 32) | (quy << 44) | (1ULL << 56);
    atomicAdd(acc + (size_t)d * 3, w);
}

__global__ void __launch_bounds__(256) node_finalize_kernel(
    const float* __restrict__ pos, float* __restrict__ out)
{
    int i = blockIdx.x * blockDim.x + threadIdx.x;
    if (i >= N_NODES) return;
    u64 w = reinterpret_cast<const u64*>(out)[(size_t)i * 3];
    float cnt = (float)(u32)(w >> 56);
    float sdx = (float)(u32)(w & 0xFFFFULL)         * (1.0f/16.0f) - 12.0f * cnt;
    float sdy = (float)(u32)((w >> 16) & 0xFFFFULL) * (1.0f/16.0f) - 12.0f * cnt;
    float sux = (float)(u32)((w >> 32) & 0xFFFULL)  * (1.0f/16.0f) -  1.0f * cnt;
    float suy = (float)(u32)((w >> 44) & 0xFFFULL)  * (1.0f/16.0f) -  1.0f * cnt;
    float invc = 1.0f / fmaxf(cnt, 1.0f);
    float2 p = reinterpret_cast<const float2*>(pos)[i];
    float* row = out + (size_t)i * 6;
    row[0] = sdx * invc; row[1] = sdy * invc;
    row[2] = sux * invc; row[3] = suy * invc;
    row[4] = p.x; row[5] = p.y;
}

extern "C" void kernel_launch(void* const* d_in, const int* in_sizes, int n_in,
                              void* d_out, int out_size, void* d_ws, size_t ws_size,
                              hipStream_t stream)
{
    const float* pos = (const float*)d_in[0];
    const int* edge_index = (const int*)d_in[1];
    const int* src = edge_index;
    const int* dst = edge_index + N_EDGES;
    float* out = (float*)d_out;

    size_t need_rec  = (size_t)NBLK_A * CHUNK * sizeof(u32);                // ~64 MB
    size_t need_incl = (size_t)NBLK_A * NBINS * sizeof(u32);                // ~4 MB
    size_t need_part = (size_t)NBINS * SPLIT * NODES_PER_BIN * sizeof(u64); // 32 MB
    size_t need = need_rec + need_incl + need_part + 256;

    if (ws_size < need) {
        // Fallback: single-u64-atomic path (round 3)
        (void)hipMemsetAsync(d_out, 0, (size_t)out_size * sizeof(float), stream);
        int eblocks = (N_EDGES + 255) / 256;
        edge_scatter_kernel<<<eblocks, 256, 0, stream>>>(
            src, dst, pos, reinterpret_cast<u64*>(out));
        int nblocks = (N_NODES + 255) / 256;
        node_finalize_kernel<<<nblocks, 256, 0, stream>>>(pos, out);
        return;
    }

    char* w = (char*)d_ws;
    u32* recbuf  = (u32*)w;           w += need_rec;
    u32* inclbuf = (u32*)w;           w += need_incl;
    u64* partial = (u64*)w;

    scatter_kernel<<<NBLK_A, 512, 0, stream>>>(src, dst, recbuf, inclbuf);
    reduce_kernel <<<NBINS * SPLIT, 512, 0, stream>>>(recbuf, inclbuf, pos, partial);
    combine_kernel<<<(N_NODES + 511) / 512, 512, 0, stream>>>(partial, pos, out);
}

// Round 18
// 220.721 us; speedup vs baseline: 1.0369x; 1.0369x over previous
//
#include <hip/hip_runtime.h>
#include <math.h>

#define N_NODES   500000
#define N_EDGES   16000000
#define EPS       1e-6f

#define NBINS         256      // bin = dst >> 11  (2048 nodes per bin)
#define NODES_PER_BIN 2048
#define CHUNK         8192     // edges per hist/scatter block
#define NBLK_A        1954     // ceil(16e6 / 8192)
#define SPLIT         8        // reduce splits per bin

typedef unsigned long long u64;
typedef unsigned int u32;
typedef unsigned short u16;
typedef u32 v4u __attribute__((ext_vector_type(4)));

// u32 record: [0:11) lid = dst & 2047, [11:30) srcid, [30:32) spare.
// recbuf is GLOBALLY bin-contiguous (bin k occupies [S[k], S[k]+Tlen[k])),
// S[k] padded to multiples of 4 records for aligned v4u reduce loads.

// ---- Phase A1: per-(block,bin) histogram (dst only) ----
__global__ void __launch_bounds__(512) hist_kernel(
    const int* __restrict__ dst, u32* __restrict__ counts)
{
    __shared__ u32 hist[NBINS];
    int t = threadIdx.x, b = blockIdx.x;
    if (t < NBINS) hist[t] = 0;
    __syncthreads();
    const v4u* dst4 = reinterpret_cast<const v4u*>(dst);
    int base4 = b * (CHUNK / 4);
    #pragma unroll
    for (int i = 0; i < 4; ++i) {
        int e4 = base4 + t + i * 512;
        if (e4 * 4 < N_EDGES) {
            v4u d4 = __builtin_nontemporal_load(dst4 + e4);
            #pragma unroll
            for (int j = 0; j < 4; ++j) {
                u32 d_ = (u32)min(max((int)d4[j], 0), N_NODES - 1);
                atomicAdd(&hist[d_ >> 11], 1u);
            }
        }
    }
    __syncthreads();
    if (t < NBINS) counts[(size_t)b * NBINS + t] = hist[t];
}

// ---- Phase A2a: per-bin exclusive prefix over blocks (in place) + totals ----
__global__ void __launch_bounds__(256) scanblk_kernel(
    u32* __restrict__ counts, u32* __restrict__ T)
{
    __shared__ u32 sb[256];
    int t = threadIdx.x, k = blockIdx.x;
    u32 c[8], l[8];
    u32 s = 0;
    #pragma unroll
    for (int i = 0; i < 8; ++i) {
        int b = t * 8 + i;
        c[i] = (b < NBLK_A) ? counts[(size_t)b * NBINS + k] : 0;
        l[i] = s;
        s += c[i];
    }
    sb[t] = s;
    __syncthreads();
    for (int off = 1; off < 256; off <<= 1) {
        u32 v = sb[t];
        u32 a = (t >= off) ? sb[t - off] : 0;
        __syncthreads();
        sb[t] = v + a;
        __syncthreads();
    }
    u32 excl = sb[t] - s;
    #pragma unroll
    for (int i = 0; i < 8; ++i) {
        int b = t * 8 + i;
        if (b < NBLK_A) counts[(size_t)b * NBINS + k] = excl + l[i];
    }
    if (t == 255) T[k] = sb[255];
}

// ---- Phase A2b: padded exclusive scan of bin totals -> S, keep lengths ----
__global__ void __launch_bounds__(NBINS) scanbin_kernel(
    const u32* __restrict__ T, u32* __restrict__ S, u32* __restrict__ Tlen)
{
    __shared__ u32 sb[NBINS];
    int t = threadIdx.x;
    u32 own = T[t];
    u32 p4 = (own + 3u) & ~3u;          // pad each bin to x4 records
    sb[t] = p4;
    __syncthreads();
    for (int off = 1; off < NBINS; off <<= 1) {
        u32 v = sb[t];
        u32 a = (t >= off) ? sb[t - off] : 0;
        __syncthreads();
        sb[t] = v + a;
        __syncthreads();
    }
    if (t == 0) S[0] = 0;
    S[t + 1] = sb[t];
    Tlen[t] = own;
}

// ---- Phase A3: integer counting sort with GLOBAL bin-contiguous writeout ----
__global__ void __launch_bounds__(512) scatter_kernel(
    const int* __restrict__ src, const int* __restrict__ dst,
    const u32* __restrict__ P, const u32* __restrict__ S,
    u32* __restrict__ recbuf)
{
    __shared__ u32 stage[CHUNK];       // 32 KB — records at arrival slot
    __shared__ u16 perm[CHUNK];        // 16 KB — sorted pos -> slot
    __shared__ u32 incl[NBINS];        // 1 KB
    __shared__ u32 gbase[NBINS];       // 1 KB
    __shared__ u32 wsum[4];

    int t = threadIdx.x, b = blockIdx.x;
    int lane = t & 63, wid = t >> 6;
    if (t < NBINS) {
        gbase[t] = S[t] + P[(size_t)b * NBINS + t];
        incl[t] = 0;
    }
    __syncthreads();

    const v4u* src4 = reinterpret_cast<const v4u*>(src);
    const v4u* dst4 = reinterpret_cast<const v4u*>(dst);
    int base4 = b * (CHUNK / 4);

    u32 rb[16];                        // bin(8) << 13 | rank(13); ~0u = invalid
    #pragma unroll
    for (int i = 0; i < 4; ++i) {
        int e4 = base4 + t + i * 512;
        #pragma unroll
        for (int j = 0; j < 4; ++j) rb[i * 4 + j] = 0xFFFFFFFFu;
        if (e4 * 4 < N_EDGES) {
            v4u s4 = __builtin_nontemporal_load(src4 + e4);
            v4u d4 = __builtin_nontemporal_load(dst4 + e4);
            #pragma unroll
            for (int j = 0; j < 4; ++j) {
                u32 s_ = (u32)min(max((int)s4[j], 0), N_NODES - 1);
                u32 d_ = (u32)min(max((int)d4[j], 0), N_NODES - 1);
                u32 rc = (s_ << 11) | (d_ & (NODES_PER_BIN - 1));
                int kk = i * 4 + j;
                stage[t + kk * 512] = rc;
                u32 bin = d_ >> 11;
                u32 r = atomicAdd(&incl[bin], 1u);
                rb[kk] = (bin << 13) | r;
            }
        }
    }
    __syncthreads();

    // inclusive scan of incl[256] (4 waves)
    u32 v = 0;
    if (t < NBINS) {
        v = incl[t];
        #pragma unroll
        for (int off = 1; off < 64; off <<= 1) {
            u32 u_ = __shfl_up(v, off, 64);
            if (lane >= off) v += u_;
        }
        if (lane == 63) wsum[wid] = v;
    }
    __syncthreads();
    if (t < NBINS) {
        u32 pre = 0;
        #pragma unroll
        for (int w2 = 0; w2 < 4; ++w2)
            pre += (w2 < wid) ? wsum[w2] : 0;
        v += pre;
        incl[t] = v;
    }
    __syncthreads();

    #pragma unroll
    for (int kk = 0; kk < 16; ++kk) {
        if (rb[kk] != 0xFFFFFFFFu) {
            u32 bin = rb[kk] >> 13;
            u32 r   = rb[kk] & 8191u;
            u32 excl = bin ? incl[bin - 1] : 0;
            perm[excl + r] = (u16)(t + kk * 512);
        }
    }
    __syncthreads();

    // writeout to global bin-contiguous regions (runs avg 32 -> mostly coalesced)
    u32 total = incl[NBINS - 1];
    for (u32 j = t; j < total; j += 512) {
        u32 rc = stage[perm[j]];
        u32 lo = 0, hi = NBINS - 1;
        #pragma unroll
        for (int it = 0; it < 8; ++it) {
            u32 mid = (lo + hi) >> 1;
            if (j < incl[mid]) hi = mid; else lo = mid + 1;
        }
        u32 excl = lo ? incl[lo - 1] : 0;
        recbuf[gbase[lo] + (j - excl)] = rc;
    }
}

// ---- Phase B: flat split-K decode + accumulate (MLP-4, no directory) ----
__global__ void __launch_bounds__(512) reduce_kernel(
    const u32* __restrict__ recbuf, const u32* __restrict__ S,
    const u32* __restrict__ Tlen, const float* __restrict__ pos,
    u64* __restrict__ partial)
{
    __shared__ u64 acc[NODES_PER_BIN];   // 16 KB
    int t = threadIdx.x;
    int k = blockIdx.x / SPLIT;
    int s = blockIdx.x % SPLIT;
    #pragma unroll
    for (int i = 0; i < 4; ++i) acc[t + i * 512] = 0;
    __syncthreads();

    u32 base = S[k];                     // 4-record aligned
    u32 len  = Tlen[k];
    u32 lo = (u32)(((u64)len * s / SPLIT) & ~3ull);
    u32 hi = (s == SPLIT - 1) ? len : (u32)(((u64)len * (s + 1) / SPLIT) & ~3ull);

    const float2* pos2 = reinterpret_cast<const float2*>(pos);
    int nodebase = k * NODES_PER_BIN;
    const u32* seg = recbuf + base;

    for (u32 j = lo + (u32)t * 4; j < hi; j += 2048) {
        v4u r4 = *reinterpret_cast<const v4u*>(seg + j);   // aligned 16B
        u32 n = hi - j;                                     // valid count (>=1)
        #pragma unroll
        for (int i = 0; i < 4; ++i) {
            u32 rc = r4[i];
            u32 lid = rc & (NODES_PER_BIN - 1);
            u32 sx  = min(rc >> 11, (u32)(N_NODES - 1));            // clamp garbage
            u32 dxi = min((u32)(nodebase + lid), (u32)(N_NODES - 1));
            float2 ps = pos2[sx];
            float2 pd = pos2[dxi];
            float dx = ps.x - pd.x;
            float dy = ps.y - pd.y;
            float nrm = sqrtf(dx * dx + dy * dy) + EPS;
            float inv = 1.0f / nrm;
            float ux = dx * inv, uy = dy * inv;
            float cdx = fminf(fmaxf(dx, -12.0f), 12.0f);
            float cdy = fminf(fmaxf(dy, -12.0f), 12.0f);
            u32 qdx = (u32)__float2int_rn((cdx + 12.0f) * 16.0f);
            u32 qdy = (u32)__float2int_rn((cdy + 12.0f) * 16.0f);
            u32 qux = (u32)__float2int_rn((ux + 1.0f) * 16.0f);
            u32 quy = (u32)__float2int_rn((uy + 1.0f) * 16.0f);
            u64 w = (u64)qdx | ((u64)qdy << 16) | ((u64)qux << 32)
                  | ((u64)quy << 44) | (1ULL << 56);
            if ((u32)i < n) atomicAdd(&acc[lid], w);
        }
    }
    __syncthreads();

    u64* dstp = partial + ((size_t)k * SPLIT + s) * NODES_PER_BIN;
    #pragma unroll
    for (int i = 0; i < 4; ++i) {
        int idx = t + i * 512;
        __builtin_nontemporal_store(acc[idx], dstp + idx);
    }
}

// ---- Phase C: combine partials + finalize ----
__global__ void __launch_bounds__(512) combine_kernel(
    const u64* __restrict__ partial, const float* __restrict__ pos,
    float* __restrict__ out)
{
    int i = blockIdx.x * 512 + threadIdx.x;
    if (i >= N_NODES) return;
    int k = i >> 11;
    int lid = i & (NODES_PER_BIN - 1);
    const u64* p = partial + (size_t)k * SPLIT * NODES_PER_BIN + lid;
    u64 w = 0;
    #pragma unroll
    for (int s = 0; s < SPLIT; ++s)
        w += __builtin_nontemporal_load(p + (size_t)s * NODES_PER_BIN);

    float cnt = (float)(u32)(w >> 56);
    float sdx = (float)(u32)(w & 0xFFFFULL)         * (1.0f/16.0f) - 12.0f * cnt;
    float sdy = (float)(u32)((w >> 16) & 0xFFFFULL) * (1.0f/16.0f) - 12.0f * cnt;
    float sux = (float)(u32)((w >> 32) & 0xFFFULL)  * (1.0f/16.0f) -  1.0f * cnt;
    float suy = (float)(u32)((w >> 44) & 0xFFFULL)  * (1.0f/16.0f) -  1.0f * cnt;
    float invc = 1.0f / fmaxf(cnt, 1.0f);
    float2 pp = reinterpret_cast<const float2*>(pos)[i];
    float* row = out + (size_t)i * 6;
    row[0] = sdx * invc;
    row[1] = sdy * invc;
    row[2] = sux * invc;
    row[3] = suy * invc;
    row[4] = pp.x;
    row[5] = pp.y;
}

// ---------------- Fallback (round-3 single-atomic path) ----------------
__global__ void __launch_bounds__(256) edge_scatter_kernel(
    const int* __restrict__ src, const int* __restrict__ dst,
    const float* __restrict__ pos, u64* __restrict__ acc)
{
    int e = blockIdx.x * blockDim.x + threadIdx.x;
    if (e >= N_EDGES) return;
    int s = src[e];
    int d = dst[e];
    if ((unsigned)s >= (unsigned)N_NODES || (unsigned)d >= (unsigned)N_NODES) return;
    float2 ps = reinterpret_cast<const float2*>(pos)[s];
    float2 pd = reinterpret_cast<const float2*>(pos)[d];
    float dx = ps.x - pd.x, dy = ps.y - pd.y;
    float nrm = sqrtf(dx*dx + dy*dy) + EPS;
    float inv = 1.0f / nrm;
    float ux = dx * inv, uy = dy * inv;
    float cdx = fminf(fmaxf(dx, -12.0f), 12.0f);
    float cdy = fminf(fmaxf(dy, -12.0f), 12.0f);
    u64 qdx = (u64)(u32)__float2int_rn((cdx + 12.0f) * 16.0f);
    u64 qdy = (u64)(u32)__float2int_rn((cdy + 12.0f) * 16.0f);
    u64 qux = (u64)(u32)__float2int_rn((ux + 1.0f) * 16.0f);
    u64 quy = (u64)(u32)__float2int_rn((uy + 1.0f) * 16.0f);
    u64 w = qdx | (qdy << 16) | (qux << 32) | (quy << 44) | (1ULL << 56);
    atomicAdd(acc + (size_t)d * 3, w);
}

__global__ void __launch_bounds__(256) node_finalize_kernel(
    const float* __restrict__ pos, float* __restrict__ out)
{
    int i = blockIdx.x * blockDim.x + threadIdx.x;
    if (i >= N_NODES) return;
    u64 w = reinterpret_cast<const u64*>(out)[(size_t)i * 3];
    float cnt = (float)(u32)(w >> 56);
    float sdx = (float)(u32)(w & 0xFFFFULL)         * (1.0f/16.0f) - 12.0f * cnt;
    float sdy = (float)(u32)((w >> 16) & 0xFFFFULL) * (1.0f/16.0f) - 12.0f * cnt;
    float sux = (float)(u32)((w >> 32) & 0xFFFULL)  * (1.0f/16.0f) -  1.0f * cnt;
    float suy = (float)(u32)((w >> 44) & 0xFFFULL)  * (1.0f/16.0f) -  1.0f * cnt;
    float invc = 1.0f / fmaxf(cnt, 1.0f);
    float2 p = reinterpret_cast<const float2*>(pos)[i];
    float* row = out + (size_t)i * 6;
    row[0] = sdx * invc; row[1] = sdy * invc;
    row[2] = sux * invc; row[3] = suy * invc;
    row[4] = p.x; row[5] = p.y;
}

extern "C" void kernel_launch(void* const* d_in, const int* in_sizes, int n_in,
                              void* d_out, int out_size, void* d_ws, size_t ws_size,
                              hipStream_t stream)
{
    const float* pos = (const float*)d_in[0];
    const int* edge_index = (const int*)d_in[1];
    const int* src = edge_index;
    const int* dst = edge_index + N_EDGES;
    float* out = (float*)d_out;

    size_t need_rec    = ((size_t)N_EDGES + 4 * NBINS + 16) * sizeof(u32);      // ~64 MB
    size_t need_counts = (size_t)NBLK_A * NBINS * sizeof(u32);                  // ~2 MB
    size_t need_T      = (size_t)NBINS * sizeof(u32);
    size_t need_S      = (size_t)(NBINS + 1) * sizeof(u32);
    size_t need_Tlen   = (size_t)NBINS * sizeof(u32);
    size_t need_part   = (size_t)NBINS * SPLIT * NODES_PER_BIN * sizeof(u64);   // 32 MB
    size_t need = need_rec + need_counts + need_T + need_S + need_Tlen + need_part + 512;

    if (ws_size < need) {
        // Fallback: single-u64-atomic path (round 3)
        (void)hipMemsetAsync(d_out, 0, (size_t)out_size * sizeof(float), stream);
        int eblocks = (N_EDGES + 255) / 256;
        edge_scatter_kernel<<<eblocks, 256, 0, stream>>>(
            src, dst, pos, reinterpret_cast<u64*>(out));
        int nblocks = (N_NODES + 255) / 256;
        node_finalize_kernel<<<nblocks, 256, 0, stream>>>(pos, out);
        return;
    }

    char* w = (char*)d_ws;
    u32* recbuf  = (u32*)w;           w += need_rec;
    u32* counts  = (u32*)w;           w += need_counts;
    u32* T       = (u32*)w;           w += need_T;
    u32* S       = (u32*)w;           w += need_S;
    u32* Tlen    = (u32*)w;           w += need_Tlen;
    u64* partial = (u64*)w;

    hist_kernel   <<<NBLK_A, 512, 0, stream>>>(dst, counts);
    scanblk_kernel<<<NBINS,  256, 0, stream>>>(counts, T);
    scanbin_kernel<<<1,    NBINS, 0, stream>>>(T, S, Tlen);
    scatter_kernel<<<NBLK_A, 512, 0, stream>>>(src, dst, counts, S, recbuf);
    reduce_kernel <<<NBINS * SPLIT, 512, 0, stream>>>(recbuf, S, Tlen, pos, partial);
    combine_kernel<<<(N_NODES + 511) / 512, 512, 0, stream>>>(partial, pos, out);
}

// Round 19
// 209.338 us; speedup vs baseline: 1.0933x; 1.0544x over previous
//
#include <hip/hip_runtime.h>
#include <math.h>

#define N_NODES   500000
#define N_EDGES   16000000
#define EPS       1e-6f

#define NBINS         256      // bin = dst >> 11  (2048 nodes per bin)
#define NODES_PER_BIN 2048
#define CHUNK         8192     // edges per hist/scatter block
#define NBLK_A        1954     // ceil(16e6 / 8192)
#define SPLIT         8        // reduce splits per bin

typedef unsigned long long u64;
typedef unsigned int u32;
typedef unsigned short u16;
typedef u32 v4u __attribute__((ext_vector_type(4)));

// u32 record: [0:11) lid = dst & 2047, [11:30) srcid, [30:32) spare.
// recbuf is GLOBALLY bin-contiguous; S[k] padded to x4 records.

// ---- Phase A1: per-(block,bin) histogram (dst only) ----
__global__ void __launch_bounds__(512) hist_kernel(
    const int* __restrict__ dst, u32* __restrict__ counts)
{
    __shared__ u32 hist[NBINS];
    int t = threadIdx.x, b = blockIdx.x;
    if (t < NBINS) hist[t] = 0;
    __syncthreads();
    const v4u* dst4 = reinterpret_cast<const v4u*>(dst);
    int base4 = b * (CHUNK / 4);
    #pragma unroll
    for (int i = 0; i < 4; ++i) {
        int e4 = base4 + t + i * 512;
        if (e4 * 4 < N_EDGES) {
            v4u d4 = __builtin_nontemporal_load(dst4 + e4);
            #pragma unroll
            for (int j = 0; j < 4; ++j) {
                u32 d_ = (u32)min(max((int)d4[j], 0), N_NODES - 1);
                atomicAdd(&hist[d_ >> 11], 1u);
            }
        }
    }
    __syncthreads();
    if (t < NBINS) counts[(size_t)b * NBINS + t] = hist[t];
}

// ---- Phase A2a: per-bin exclusive prefix over blocks (in place) + totals ----
__global__ void __launch_bounds__(256) scanblk_kernel(
    u32* __restrict__ counts, u32* __restrict__ T)
{
    __shared__ u32 sb[256];
    int t = threadIdx.x, k = blockIdx.x;
    u32 c[8], l[8];
    u32 s = 0;
    #pragma unroll
    for (int i = 0; i < 8; ++i) {
        int b = t * 8 + i;
        c[i] = (b < NBLK_A) ? counts[(size_t)b * NBINS + k] : 0;
        l[i] = s;
        s += c[i];
    }
    sb[t] = s;
    __syncthreads();
    for (int off = 1; off < 256; off <<= 1) {
        u32 v = sb[t];
        u32 a = (t >= off) ? sb[t - off] : 0;
        __syncthreads();
        sb[t] = v + a;
        __syncthreads();
    }
    u32 excl = sb[t] - s;
    #pragma unroll
    for (int i = 0; i < 8; ++i) {
        int b = t * 8 + i;
        if (b < NBLK_A) counts[(size_t)b * NBINS + k] = excl + l[i];
    }
    if (t == 255) T[k] = sb[255];
}

// ---- Phase A2b: padded exclusive scan of bin totals -> S, keep lengths ----
__global__ void __launch_bounds__(NBINS) scanbin_kernel(
    const u32* __restrict__ T, u32* __restrict__ S, u32* __restrict__ Tlen)
{
    __shared__ u32 sb[NBINS];
    int t = threadIdx.x;
    u32 own = T[t];
    u32 p4 = (own + 3u) & ~3u;          // pad each bin to x4 records
    sb[t] = p4;
    __syncthreads();
    for (int off = 1; off < NBINS; off <<= 1) {
        u32 v = sb[t];
        u32 a = (t >= off) ? sb[t - off] : 0;
        __syncthreads();
        sb[t] = v + a;
        __syncthreads();
    }
    if (t == 0) S[0] = 0;
    S[t + 1] = sb[t];
    Tlen[t] = own;
}

// ---- Phase A3: integer counting sort with GLOBAL bin-contiguous writeout ----
__global__ void __launch_bounds__(512) scatter_kernel(
    const int* __restrict__ src, const int* __restrict__ dst,
    const u32* __restrict__ P, const u32* __restrict__ S,
    u32* __restrict__ recbuf)
{
    __shared__ u32 stage[CHUNK];       // 32 KB — records at arrival slot
    __shared__ u16 perm[CHUNK];        // 16 KB — sorted pos -> slot
    __shared__ u32 incl[NBINS];        // 1 KB
    __shared__ u32 gbase[NBINS];       // 1 KB
    __shared__ u32 wsum[4];

    int t = threadIdx.x, b = blockIdx.x;
    int lane = t & 63, wid = t >> 6;
    if (t < NBINS) {
        gbase[t] = S[t] + P[(size_t)b * NBINS + t];
        incl[t] = 0;
    }
    __syncthreads();

    const v4u* src4 = reinterpret_cast<const v4u*>(src);
    const v4u* dst4 = reinterpret_cast<const v4u*>(dst);
    int base4 = b * (CHUNK / 4);

    u32 rb[16];                        // bin(8) << 13 | rank(13); ~0u = invalid
    #pragma unroll
    for (int i = 0; i < 4; ++i) {
        int e4 = base4 + t + i * 512;
        #pragma unroll
        for (int j = 0; j < 4; ++j) rb[i * 4 + j] = 0xFFFFFFFFu;
        if (e4 * 4 < N_EDGES) {
            v4u s4 = __builtin_nontemporal_load(src4 + e4);
            v4u d4 = __builtin_nontemporal_load(dst4 + e4);
            #pragma unroll
            for (int j = 0; j < 4; ++j) {
                u32 s_ = (u32)min(max((int)s4[j], 0), N_NODES - 1);
                u32 d_ = (u32)min(max((int)d4[j], 0), N_NODES - 1);
                u32 rc = (s_ << 11) | (d_ & (NODES_PER_BIN - 1));
                int kk = i * 4 + j;
                stage[t + kk * 512] = rc;
                u32 bin = d_ >> 11;
                u32 r = atomicAdd(&incl[bin], 1u);
                rb[kk] = (bin << 13) | r;
            }
        }
    }
    __syncthreads();

    // inclusive scan of incl[256] (4 waves)
    u32 v = 0;
    if (t < NBINS) {
        v = incl[t];
        #pragma unroll
        for (int off = 1; off < 64; off <<= 1) {
            u32 u_ = __shfl_up(v, off, 64);
            if (lane >= off) v += u_;
        }
        if (lane == 63) wsum[wid] = v;
    }
    __syncthreads();
    if (t < NBINS) {
        u32 pre = 0;
        #pragma unroll
        for (int w2 = 0; w2 < 4; ++w2)
            pre += (w2 < wid) ? wsum[w2] : 0;
        v += pre;
        incl[t] = v;
    }
    __syncthreads();

    #pragma unroll
    for (int kk = 0; kk < 16; ++kk) {
        if (rb[kk] != 0xFFFFFFFFu) {
            u32 bin = rb[kk] >> 13;
            u32 r   = rb[kk] & 8191u;
            u32 excl = bin ? incl[bin - 1] : 0;
            perm[excl + r] = (u16)(t + kk * 512);
        }
    }
    __syncthreads();

    // writeout to global bin-contiguous regions
    u32 total = incl[NBINS - 1];
    for (u32 j = t; j < total; j += 512) {
        u32 rc = stage[perm[j]];
        u32 lo = 0, hi = NBINS - 1;
        #pragma unroll
        for (int it = 0; it < 8; ++it) {
            u32 mid = (lo + hi) >> 1;
            if (j < incl[mid]) hi = mid; else lo = mid + 1;
        }
        u32 excl = lo ? incl[lo - 1] : 0;
        recbuf[gbase[lo] + (j - excl)] = rc;
    }
}

// ---- Phase B: flat split-K decode + accumulate, asm-forced MLP-4 ----
__global__ void __launch_bounds__(512) reduce_kernel(
    const u32* __restrict__ recbuf, const u32* __restrict__ S,
    const u32* __restrict__ Tlen, const float* __restrict__ pos,
    u64* __restrict__ partial)
{
    __shared__ u64 acc[NODES_PER_BIN];   // 16 KB
    int t = threadIdx.x;
    int k = blockIdx.x / SPLIT;
    int s = blockIdx.x % SPLIT;
    #pragma unroll
    for (int i = 0; i < 4; ++i) acc[t + i * 512] = 0;
    __syncthreads();

    u32 base = S[k];                     // 4-record aligned
    u32 len  = Tlen[k];
    u32 lo = (u32)(((u64)len * s / SPLIT) & ~3ull);
    u32 hi = (s == SPLIT - 1) ? len : (u32)(((u64)len * (s + 1) / SPLIT) & ~3ull);

    const float2* pos2 = reinterpret_cast<const float2*>(pos);
    int nodebase = k * NODES_PER_BIN;
    const u32* seg = recbuf + base;

    for (u32 j = lo + (u32)t * 4; j < hi; j += 2048) {
        v4u r4 = *reinterpret_cast<const v4u*>(seg + j);   // aligned 16B
        u32 n = hi - j;
        u32 rc0 = r4[0], rc1 = r4[1], rc2 = r4[2], rc3 = r4[3];
        u32 lid0 = rc0 & (NODES_PER_BIN - 1), sx0 = min(rc0 >> 11, (u32)(N_NODES - 1));
        u32 lid1 = rc1 & (NODES_PER_BIN - 1), sx1 = min(rc1 >> 11, (u32)(N_NODES - 1));
        u32 lid2 = rc2 & (NODES_PER_BIN - 1), sx2 = min(rc2 >> 11, (u32)(N_NODES - 1));
        u32 lid3 = rc3 & (NODES_PER_BIN - 1), sx3 = min(rc3 >> 11, (u32)(N_NODES - 1));

        // force 4 independent gathers into flight (compiler refuses at source
        // level: VGPR=12 in r16/r18 = serialized). One waitcnt for all 4.
        float2 ps0, ps1, ps2, ps3;
        asm volatile(
            "global_load_dwordx2 %0, %4, off\n\t"
            "global_load_dwordx2 %1, %5, off\n\t"
            "global_load_dwordx2 %2, %6, off\n\t"
            "global_load_dwordx2 %3, %7, off\n\t"
            "s_waitcnt vmcnt(0)"
            : "=&v"(ps0), "=&v"(ps1), "=&v"(ps2), "=&v"(ps3)
            : "v"(pos2 + sx0), "v"(pos2 + sx1), "v"(pos2 + sx2), "v"(pos2 + sx3));

        float2 pd0 = pos2[nodebase + lid0];
        float2 pd1 = pos2[nodebase + lid1];
        float2 pd2 = pos2[nodebase + lid2];
        float2 pd3 = pos2[nodebase + lid3];

        {
            float dx = ps0.x - pd0.x, dy = ps0.y - pd0.y;
            float nrm = sqrtf(dx * dx + dy * dy) + EPS;
            float inv = 1.0f / nrm;
            float ux = dx * inv, uy = dy * inv;
            float cdx = fminf(fmaxf(dx, -12.0f), 12.0f);
            float cdy = fminf(fmaxf(dy, -12.0f), 12.0f);
            u64 w = (u64)(u32)__float2int_rn((cdx + 12.0f) * 16.0f)
                  | ((u64)(u32)__float2int_rn((cdy + 12.0f) * 16.0f) << 16)
                  | ((u64)(u32)__float2int_rn((ux + 1.0f) * 16.0f) << 32)
                  | ((u64)(u32)__float2int_rn((uy + 1.0f) * 16.0f) << 44)
                  | (1ULL << 56);
            atomicAdd(&acc[lid0], w);
        }
        if (n > 1) {
            float dx = ps1.x - pd1.x, dy = ps1.y - pd1.y;
            float nrm = sqrtf(dx * dx + dy * dy) + EPS;
            float inv = 1.0f / nrm;
            float ux = dx * inv, uy = dy * inv;
            float cdx = fminf(fmaxf(dx, -12.0f), 12.0f);
            float cdy = fminf(fmaxf(dy, -12.0f), 12.0f);
            u64 w = (u64)(u32)__float2int_rn((cdx + 12.0f) * 16.0f)
                  | ((u64)(u32)__float2int_rn((cdy + 12.0f) * 16.0f) << 16)
                  | ((u64)(u32)__float2int_rn((ux + 1.0f) * 16.0f) << 32)
                  | ((u64)(u32)__float2int_rn((uy + 1.0f) * 16.0f) << 44)
                  | (1ULL << 56);
            atomicAdd(&acc[lid1], w);
        }
        if (n > 2) {
            float dx = ps2.x - pd2.x, dy = ps2.y - pd2.y;
            float nrm = sqrtf(dx * dx + dy * dy) + EPS;
            float inv = 1.0f / nrm;
            float ux = dx * inv, uy = dy * inv;
            float cdx = fminf(fmaxf(dx, -12.0f), 12.0f);
            float cdy = fminf(fmaxf(dy, -12.0f), 12.0f);
            u64 w = (u64)(u32)__float2int_rn((cdx + 12.0f) * 16.0f)
                  | ((u64)(u32)__float2int_rn((cdy + 12.0f) * 16.0f) << 16)
                  | ((u64)(u32)__float2int_rn((ux + 1.0f) * 16.0f) << 32)
                  | ((u64)(u32)__float2int_rn((uy + 1.0f) * 16.0f) << 44)
                  | (1ULL << 56);
            atomicAdd(&acc[lid2], w);
        }
        if (n > 3) {
            float dx = ps3.x - pd3.x, dy = ps3.y - pd3.y;
            float nrm = sqrtf(dx * dx + dy * dy) + EPS;
            float inv = 1.0f / nrm;
            float ux = dx * inv, uy = dy * inv;
            float cdx = fminf(fmaxf(dx, -12.0f), 12.0f);
            float cdy = fminf(fmaxf(dy, -12.0f), 12.0f);
            u64 w = (u64)(u32)__float2int_rn((cdx + 12.0f) * 16.0f)
                  | ((u64)(u32)__float2int_rn((cdy + 12.0f) * 16.0f) << 16)
                  | ((u64)(u32)__float2int_rn((ux + 1.0f) * 16.0f) << 32)
                  | ((u64)(u32)__float2int_rn((uy + 1.0f) * 16.0f) << 44)
                  | (1ULL << 56);
            atomicAdd(&acc[lid3], w);
        }
    }
    __syncthreads();

    u64* dstp = partial + ((size_t)k * SPLIT + s) * NODES_PER_BIN;
    #pragma unroll
    for (int i = 0; i < 4; ++i) {
        int idx = t + i * 512;
        __builtin_nontemporal_store(acc[idx], dstp + idx);
    }
}

// ---- Phase C: combine partials + finalize ----
__global__ void __launch_bounds__(512) combine_kernel(
    const u64* __restrict__ partial, const float* __restrict__ pos,
    float* __restrict__ out)
{
    int i = blockIdx.x * 512 + threadIdx.x;
    if (i >= N_NODES) return;
    int k = i >> 11;
    int lid = i & (NODES_PER_BIN - 1);
    const u64* p = partial + (size_t)k * SPLIT * NODES_PER_BIN + lid;
    u64 w = 0;
    #pragma unroll
    for (int s = 0; s < SPLIT; ++s)
        w += __builtin_nontemporal_load(p + (size_t)s * NODES_PER_BIN);

    float cnt = (float)(u32)(w >> 56);
    float sdx = (float)(u32)(w & 0xFFFFULL)         * (1.0f/16.0f) - 12.0f * cnt;
    float sdy = (float)(u32)((w >> 16) & 0xFFFFULL) * (1.0f/16.0f) - 12.0f * cnt;
    float sux = (float)(u32)((w >> 32) & 0xFFFULL)  * (1.0f/16.0f) -  1.0f * cnt;
    float suy = (float)(u32)((w >> 44) & 0xFFFULL)  * (1.0f/16.0f) -  1.0f * cnt;
    float invc = 1.0f / fmaxf(cnt, 1.0f);
    float2 pp = reinterpret_cast<const float2*>(pos)[i];
    float* row = out + (size_t)i * 6;
    row[0] = sdx * invc;
    row[1] = sdy * invc;
    row[2] = sux * invc;
    row[3] = suy * invc;
    row[4] = pp.x;
    row[5] = pp.y;
}

// ---------------- Fallback (round-3 single-atomic path) ----------------
__global__ void __launch_bounds__(256) edge_scatter_kernel(
    const int* __restrict__ src, const int* __restrict__ dst,
    const float* __restrict__ pos, u64* __restrict__ acc)
{
    int e = blockIdx.x * blockDim.x + threadIdx.x;
    if (e >= N_EDGES) return;
    int s = src[e];
    int d = dst[e];
    if ((unsigned)s >= (unsigned)N_NODES || (unsigned)d >= (unsigned)N_NODES) return;
    float2 ps = reinterpret_cast<const float2*>(pos)[s];
    float2 pd = reinterpret_cast<const float2*>(pos)[d];
    float dx = ps.x - pd.x, dy = ps.y - pd.y;
    float nrm = sqrtf(dx*dx + dy*dy) + EPS;
    float inv = 1.0f / nrm;
    float ux = dx * inv, uy = dy * inv;
    float cdx = fminf(fmaxf(dx, -12.0f), 12.0f);
    float cdy = fminf(fmaxf(dy, -12.0f), 12.0f);
    u64 qdx = (u64)(u32)__float2int_rn((cdx + 12.0f) * 16.0f);
    u64 qdy = (u64)(u32)__float2int_rn((cdy + 12.0f) * 16.0f);
    u64 qux = (u64)(u32)__float2int_rn((ux + 1.0f) * 16.0f);
    u64 quy = (u64)(u32)__float2int_rn((uy + 1.0f) * 16.0f);
    u64 w = qdx | (qdy << 16) | (qux << 32) | (quy << 44) | (1ULL << 56);
    atomicAdd(acc + (size_t)d * 3, w);
}

__global__ void __launch_bounds__(256) node_finalize_kernel(
    const float* __restrict__ pos, float* __restrict__ out)
{
    int i = blockIdx.x * blockDim.x + threadIdx.x;
    if (i >= N_NODES) return;
    u64 w = reinterpret_cast<const u64*>(out)[(size_t)i * 3];
    float cnt = (float)(u32)(w >> 56);
    float sdx = (float)(u32)(w & 0xFFFFULL)         * (1.0f/16.0f) - 12.0f * cnt;
    float sdy = (float)(u32)((w >> 16) & 0xFFFFULL) * (1.0f/16.0f) - 12.0f * cnt;
    float sux = (float)(u32)((w >> 32) & 0xFFFULL)  * (1.0f/16.0f) -  1.0f * cnt;
    float suy = (float)(u32)((w >> 44) & 0xFFFULL)  * (1.0f/16.0f) -  1.0f * cnt;
    float invc = 1.0f / fmaxf(cnt, 1.0f);
    float2 p = reinterpret_cast<const float2*>(pos)[i];
    float* row = out + (size_t)i * 6;
    row[0] = sdx * invc; row[1] = sdy * invc;
    row[2] = sux * invc; row[3] = suy * invc;
    row[4] = p.x; row[5] = p.y;
}

extern "C" void kernel_launch(void* const* d_in, const int* in_sizes, int n_in,
                              void* d_out, int out_size, void* d_ws, size_t ws_size,
                              hipStream_t stream)
{
    const float* pos = (const float*)d_in[0];
    const int* edge_index = (const int*)d_in[1];
    const int* src = edge_index;
    const int* dst = edge_index + N_EDGES;
    float* out = (float*)d_out;

    size_t need_rec    = ((size_t)N_EDGES + 4 * NBINS + 16) * sizeof(u32);      // ~64 MB
    size_t need_counts = (size_t)NBLK_A * NBINS * sizeof(u32);                  // ~2 MB
    size_t need_T      = (size_t)NBINS * sizeof(u32);
    size_t need_S      = (size_t)(NBINS + 1) * sizeof(u32);
    size_t need_Tlen   = (size_t)NBINS * sizeof(u32);
    size_t need_part   = (size_t)NBINS * SPLIT * NODES_PER_BIN * sizeof(u64);   // 32 MB
    size_t need = need_rec + need_counts + need_T + need_S + need_Tlen + need_part + 512;

    if (ws_size < need) {
        // Fallback: single-u64-atomic path (round 3)
        (void)hipMemsetAsync(d_out, 0, (size_t)out_size * sizeof(float), stream);
        int eblocks = (N_EDGES + 255) / 256;
        edge_scatter_kernel<<<eblocks, 256, 0, stream>>>(
            src, dst, pos, reinterpret_cast<u64*>(out));
        int nblocks = (N_NODES + 255) / 256;
        node_finalize_kernel<<<nblocks, 256, 0, stream>>>(pos, out);
        return;
    }

    char* w = (char*)d_ws;
    u32* recbuf  = (u32*)w;           w += need_rec;
    u32* counts  = (u32*)w;           w += need_counts;
    u32* T       = (u32*)w;           w += need_T;
    u32* S       = (u32*)w;           w += need_S;
    u32* Tlen    = (u32*)w;           w += need_Tlen;
    u64* partial = (u64*)w;

    hist_kernel   <<<NBLK_A, 512, 0, stream>>>(dst, counts);
    scanblk_kernel<<<NBINS,  256, 0, stream>>>(counts, T);
    scanbin_kernel<<<1,    NBINS, 0, stream>>>(T, S, Tlen);
    scatter_kernel<<<NBLK_A, 512, 0, stream>>>(src, dst, counts, S, recbuf);
    reduce_kernel <<<NBINS * SPLIT, 512, 0, stream>>>(recbuf, S, Tlen, pos, partial);
    combine_kernel<<<(N_NODES + 511) / 512, 512, 0, stream>>>(partial, pos, out);
}

// Round 20
// 180.700 us; speedup vs baseline: 1.2666x; 1.1585x over previous
//
#include <hip/hip_runtime.h>
#include <math.h>

#define N_NODES   500000
#define N_EDGES   16000000
#define EPS       1e-6f

#define NBINS         256      // bin = dst >> 11  (2048 nodes per bin)
#define NODES_PER_BIN 2048
#define CHUNK         8192     // edges per hist/scatter block
#define NBLK_A        1954     // ceil(16e6 / 8192)
#define SPLIT         8        // reduce splits per bin

typedef unsigned long long u64;
typedef unsigned int u32;
typedef unsigned short u16;
typedef u32 v4u __attribute__((ext_vector_type(4)));

// u32 record: [0:11) lid = dst & 2047, [11:30) srcid, [30:32) spare.
// recbuf is GLOBALLY bin-contiguous; S[k] padded to x4 records.

// ---- Phase A1: per-(block,bin) histogram (dst only) ----
__global__ void __launch_bounds__(512) hist_kernel(
    const int* __restrict__ dst, u32* __restrict__ counts)
{
    __shared__ u32 hist[NBINS];
    int t = threadIdx.x, b = blockIdx.x;
    if (t < NBINS) hist[t] = 0;
    __syncthreads();
    const v4u* dst4 = reinterpret_cast<const v4u*>(dst);
    int base4 = b * (CHUNK / 4);
    #pragma unroll
    for (int i = 0; i < 4; ++i) {
        int e4 = base4 + t + i * 512;
        if (e4 * 4 < N_EDGES) {
            v4u d4 = __builtin_nontemporal_load(dst4 + e4);
            #pragma unroll
            for (int j = 0; j < 4; ++j) {
                u32 d_ = (u32)min(max((int)d4[j], 0), N_NODES - 1);
                atomicAdd(&hist[d_ >> 11], 1u);
            }
        }
    }
    __syncthreads();
    if (t < NBINS) counts[(size_t)b * NBINS + t] = hist[t];
}

// ---- Phase A2a: per-bin exclusive prefix over blocks (in place) + totals ----
__global__ void __launch_bounds__(256) scanblk_kernel(
    u32* __restrict__ counts, u32* __restrict__ T)
{
    __shared__ u32 sb[256];
    int t = threadIdx.x, k = blockIdx.x;
    u32 c[8], l[8];
    u32 s = 0;
    #pragma unroll
    for (int i = 0; i < 8; ++i) {
        int b = t * 8 + i;
        c[i] = (b < NBLK_A) ? counts[(size_t)b * NBINS + k] : 0;
        l[i] = s;
        s += c[i];
    }
    sb[t] = s;
    __syncthreads();
    for (int off = 1; off < 256; off <<= 1) {
        u32 v = sb[t];
        u32 a = (t >= off) ? sb[t - off] : 0;
        __syncthreads();
        sb[t] = v + a;
        __syncthreads();
    }
    u32 excl = sb[t] - s;
    #pragma unroll
    for (int i = 0; i < 8; ++i) {
        int b = t * 8 + i;
        if (b < NBLK_A) counts[(size_t)b * NBINS + k] = excl + l[i];
    }
    if (t == 255) T[k] = sb[255];
}

// ---- Phase A2b: padded exclusive scan of bin totals -> S, keep lengths ----
__global__ void __launch_bounds__(NBINS) scanbin_kernel(
    const u32* __restrict__ T, u32* __restrict__ S, u32* __restrict__ Tlen)
{
    __shared__ u32 sb[NBINS];
    int t = threadIdx.x;
    u32 own = T[t];
    u32 p4 = (own + 3u) & ~3u;          // pad each bin to x4 records
    sb[t] = p4;
    __syncthreads();
    for (int off = 1; off < NBINS; off <<= 1) {
        u32 v = sb[t];
        u32 a = (t >= off) ? sb[t - off] : 0;
        __syncthreads();
        sb[t] = v + a;
        __syncthreads();
    }
    if (t == 0) S[0] = 0;
    S[t + 1] = sb[t];
    Tlen[t] = own;
}

// ---- Phase A3: integer counting sort with GLOBAL bin-contiguous writeout ----
__global__ void __launch_bounds__(512) scatter_kernel(
    const int* __restrict__ src, const int* __restrict__ dst,
    const u32* __restrict__ P, const u32* __restrict__ S,
    u32* __restrict__ recbuf)
{
    __shared__ u32 stage[CHUNK];       // 32 KB — records at arrival slot
    __shared__ u16 perm[CHUNK];        // 16 KB — sorted pos -> slot
    __shared__ u32 incl[NBINS];        // 1 KB
    __shared__ u32 gbase[NBINS];       // 1 KB
    __shared__ u32 wsum[4];

    int t = threadIdx.x, b = blockIdx.x;
    int lane = t & 63, wid = t >> 6;
    if (t < NBINS) {
        gbase[t] = S[t] + P[(size_t)b * NBINS + t];
        incl[t] = 0;
    }
    __syncthreads();

    const v4u* src4 = reinterpret_cast<const v4u*>(src);
    const v4u* dst4 = reinterpret_cast<const v4u*>(dst);
    int base4 = b * (CHUNK / 4);

    u32 rb[16];                        // bin(8) << 13 | rank(13); ~0u = invalid
    #pragma unroll
    for (int i = 0; i < 4; ++i) {
        int e4 = base4 + t + i * 512;
        #pragma unroll
        for (int j = 0; j < 4; ++j) rb[i * 4 + j] = 0xFFFFFFFFu;
        if (e4 * 4 < N_EDGES) {
            v4u s4 = __builtin_nontemporal_load(src4 + e4);
            v4u d4 = __builtin_nontemporal_load(dst4 + e4);
            #pragma unroll
            for (int j = 0; j < 4; ++j) {
                u32 s_ = (u32)min(max((int)s4[j], 0), N_NODES - 1);
                u32 d_ = (u32)min(max((int)d4[j], 0), N_NODES - 1);
                u32 rc = (s_ << 11) | (d_ & (NODES_PER_BIN - 1));
                int kk = i * 4 + j;
                stage[t + kk * 512] = rc;
                u32 bin = d_ >> 11;
                u32 r = atomicAdd(&incl[bin], 1u);
                rb[kk] = (bin << 13) | r;
            }
        }
    }
    __syncthreads();

    // inclusive scan of incl[256] (4 waves)
    u32 v = 0;
    if (t < NBINS) {
        v = incl[t];
        #pragma unroll
        for (int off = 1; off < 64; off <<= 1) {
            u32 u_ = __shfl_up(v, off, 64);
            if (lane >= off) v += u_;
        }
        if (lane == 63) wsum[wid] = v;
    }
    __syncthreads();
    if (t < NBINS) {
        u32 pre = 0;
        #pragma unroll
        for (int w2 = 0; w2 < 4; ++w2)
            pre += (w2 < wid) ? wsum[w2] : 0;
        v += pre;
        incl[t] = v;
    }
    __syncthreads();

    #pragma unroll
    for (int kk = 0; kk < 16; ++kk) {
        if (rb[kk] != 0xFFFFFFFFu) {
            u32 bin = rb[kk] >> 13;
            u32 r   = rb[kk] & 8191u;
            u32 excl = bin ? incl[bin - 1] : 0;
            perm[excl + r] = (u16)(t + kk * 512);
        }
    }
    __syncthreads();

    // writeout to global bin-contiguous regions
    u32 total = incl[NBINS - 1];
    for (u32 j = t; j < total; j += 512) {
        u32 rc = stage[perm[j]];
        u32 lo = 0, hi = NBINS - 1;
        #pragma unroll
        for (int it = 0; it < 8; ++it) {
            u32 mid = (lo + hi) >> 1;
            if (j < incl[mid]) hi = mid; else lo = mid + 1;
        }
        u32 excl = lo ? incl[lo - 1] : 0;
        recbuf[gbase[lo] + (j - excl)] = rc;
    }
}

// ---- Phase B: flat split-K decode + accumulate; LDS pos window + asm MLP-4 ----
__global__ void __launch_bounds__(512) reduce_kernel(
    const u32* __restrict__ recbuf, const u32* __restrict__ S,
    const u32* __restrict__ Tlen, const float* __restrict__ pos,
    u64* __restrict__ partial)
{
    __shared__ u64 acc[NODES_PER_BIN];     // 16 KB
    __shared__ float2 pwin[NODES_PER_BIN]; // 16 KB — bin's pos window (dst side)
    int t = threadIdx.x;
    int k = blockIdx.x / SPLIT;
    int s = blockIdx.x % SPLIT;
    int nodebase = k * NODES_PER_BIN;
    const float2* pos2 = reinterpret_cast<const float2*>(pos);
    #pragma unroll
    for (int i = 0; i < 4; ++i) {
        int idx = t + i * 512;
        acc[idx] = 0;
        pwin[idx] = pos2[min(nodebase + idx, N_NODES - 1)];
    }
    __syncthreads();

    u32 base = S[k];                     // 4-record aligned
    u32 len  = Tlen[k];
    u32 lo = (u32)(((u64)len * s / SPLIT) & ~3ull);
    u32 hi = (s == SPLIT - 1) ? len : (u32)(((u64)len * (s + 1) / SPLIT) & ~3ull);

    const u32* seg = recbuf + base;

    for (u32 j = lo + (u32)t * 4; j < hi; j += 2048) {
        v4u r4 = *reinterpret_cast<const v4u*>(seg + j);   // aligned 16B
        u32 n = hi - j;
        u32 rc0 = r4[0], rc1 = r4[1], rc2 = r4[2], rc3 = r4[3];
        u32 lid0 = rc0 & (NODES_PER_BIN - 1), sx0 = min(rc0 >> 11, (u32)(N_NODES - 1));
        u32 lid1 = rc1 & (NODES_PER_BIN - 1), sx1 = min(rc1 >> 11, (u32)(N_NODES - 1));
        u32 lid2 = rc2 & (NODES_PER_BIN - 1), sx2 = min(rc2 >> 11, (u32)(N_NODES - 1));
        u32 lid3 = rc3 & (NODES_PER_BIN - 1), sx3 = min(rc3 >> 11, (u32)(N_NODES - 1));

        // force 4 independent src-pos gathers into flight; one waitcnt for all.
        float2 ps0, ps1, ps2, ps3;
        asm volatile(
            "global_load_dwordx2 %0, %4, off\n\t"
            "global_load_dwordx2 %1, %5, off\n\t"
            "global_load_dwordx2 %2, %6, off\n\t"
            "global_load_dwordx2 %3, %7, off\n\t"
            "s_waitcnt vmcnt(0)"
            : "=&v"(ps0), "=&v"(ps1), "=&v"(ps2), "=&v"(ps3)
            : "v"(pos2 + sx0), "v"(pos2 + sx1), "v"(pos2 + sx2), "v"(pos2 + sx3));

        // dst-pos from the LDS window (no TA traffic)
        float2 pd0 = pwin[lid0];
        float2 pd1 = pwin[lid1];
        float2 pd2 = pwin[lid2];
        float2 pd3 = pwin[lid3];

        {
            float dx = ps0.x - pd0.x, dy = ps0.y - pd0.y;
            float nrm = sqrtf(dx * dx + dy * dy) + EPS;
            float inv = 1.0f / nrm;
            float ux = dx * inv, uy = dy * inv;
            float cdx = fminf(fmaxf(dx, -12.0f), 12.0f);
            float cdy = fminf(fmaxf(dy, -12.0f), 12.0f);
            u64 w = (u64)(u32)__float2int_rn((cdx + 12.0f) * 16.0f)
                  | ((u64)(u32)__float2int_rn((cdy + 12.0f) * 16.0f) << 16)
                  | ((u64)(u32)__float2int_rn((ux + 1.0f) * 16.0f) << 32)
                  | ((u64)(u32)__float2int_rn((uy + 1.0f) * 16.0f) << 44)
                  | (1ULL << 56);
            atomicAdd(&acc[lid0], w);
        }
        if (n > 1) {
            float dx = ps1.x - pd1.x, dy = ps1.y - pd1.y;
            float nrm = sqrtf(dx * dx + dy * dy) + EPS;
            float inv = 1.0f / nrm;
            float ux = dx * inv, uy = dy * inv;
            float cdx = fminf(fmaxf(dx, -12.0f), 12.0f);
            float cdy = fminf(fmaxf(dy, -12.0f), 12.0f);
            u64 w = (u64)(u32)__float2int_rn((cdx + 12.0f) * 16.0f)
                  | ((u64)(u32)__float2int_rn((cdy + 12.0f) * 16.0f) << 16)
                  | ((u64)(u32)__float2int_rn((ux + 1.0f) * 16.0f) << 32)
                  | ((u64)(u32)__float2int_rn((uy + 1.0f) * 16.0f) << 44)
                  | (1ULL << 56);
            atomicAdd(&acc[lid1], w);
        }
        if (n > 2) {
            float dx = ps2.x - pd2.x, dy = ps2.y - pd2.y;
            float nrm = sqrtf(dx * dx + dy * dy) + EPS;
            float inv = 1.0f / nrm;
            float ux = dx * inv, uy = dy * inv;
            float cdx = fminf(fmaxf(dx, -12.0f), 12.0f);
            float cdy = fminf(fmaxf(dy, -12.0f), 12.0f);
            u64 w = (u64)(u32)__float2int_rn((cdx + 12.0f) * 16.0f)
                  | ((u64)(u32)__float2int_rn((cdy + 12.0f) * 16.0f) << 16)
                  | ((u64)(u32)__float2int_rn((ux + 1.0f) * 16.0f) << 32)
                  | ((u64)(u32)__float2int_rn((uy + 1.0f) * 16.0f) << 44)
                  | (1ULL << 56);
            atomicAdd(&acc[lid2], w);
        }
        if (n > 3) {
            float dx = ps3.x - pd3.x, dy = ps3.y - pd3.y;
            float nrm = sqrtf(dx * dx + dy * dy) + EPS;
            float inv = 1.0f / nrm;
            float ux = dx * inv, uy = dy * inv;
            float cdx = fminf(fmaxf(dx, -12.0f), 12.0f);
            float cdy = fminf(fmaxf(dy, -12.0f), 12.0f);
            u64 w = (u64)(u32)__float2int_rn((cdx + 12.0f) * 16.0f)
                  | ((u64)(u32)__float2int_rn((cdy + 12.0f) * 16.0f) << 16)
                  | ((u64)(u32)__float2int_rn((ux + 1.0f) * 16.0f) << 32)
                  | ((u64)(u32)__float2int_rn((uy + 1.0f) * 16.0f) << 44)
                  | (1ULL << 56);
            atomicAdd(&acc[lid3], w);
        }
    }
    __syncthreads();

    u64* dstp = partial + ((size_t)k * SPLIT + s) * NODES_PER_BIN;
    #pragma unroll
    for (int i = 0; i < 4; ++i) {
        int idx = t + i * 512;
        __builtin_nontemporal_store(acc[idx], dstp + idx);
    }
}

// ---- Phase C: combine partials + finalize ----
__global__ void __launch_bounds__(512) combine_kernel(
    const u64* __restrict__ partial, const float* __restrict__ pos,
    float* __restrict__ out)
{
    int i = blockIdx.x * 512 + threadIdx.x;
    if (i >= N_NODES) return;
    int k = i >> 11;
    int lid = i & (NODES_PER_BIN - 1);
    const u64* p = partial + (size_t)k * SPLIT * NODES_PER_BIN + lid;
    u64 w = 0;
    #pragma unroll
    for (int s = 0; s < SPLIT; ++s)
        w += __builtin_nontemporal_load(p + (size_t)s * NODES_PER_BIN);

    float cnt = (float)(u32)(w >> 56);
    float sdx = (float)(u32)(w & 0xFFFFULL)         * (1.0f/16.0f) - 12.0f * cnt;
    float sdy = (float)(u32)((w >> 16) & 0xFFFFULL) * (1.0f/16.0f) - 12.0f * cnt;
    float sux = (float)(u32)((w >> 32) & 0xFFFULL)  * (1.0f/16.0f) -  1.0f * cnt;
    float suy = (float)(u32)((w >> 44) & 0xFFFULL)  * (1.0f/16.0f) -  1.0f * cnt;
    float invc = 1.0f / fmaxf(cnt, 1.0f);
    float2 pp = reinterpret_cast<const float2*>(pos)[i];
    float* row = out + (size_t)i * 6;
    row[0] = sdx * invc;
    row[1] = sdy * invc;
    row[2] = sux * invc;
    row[3] = suy * invc;
    row[4] = pp.x;
    row[5] = pp.y;
}

// ---------------- Fallback (round-3 single-atomic path) ----------------
__global__ void __launch_bounds__(256) edge_scatter_kernel(
    const int* __restrict__ src, const int* __restrict__ dst,
    const float* __restrict__ pos, u64* __restrict__ acc)
{
    int e = blockIdx.x * blockDim.x + threadIdx.x;
    if (e >= N_EDGES) return;
    int s = src[e];
    int d = dst[e];
    if ((unsigned)s >= (unsigned)N_NODES || (unsigned)d >= (unsigned)N_NODES) return;
    float2 ps = reinterpret_cast<const float2*>(pos)[s];
    float2 pd = reinterpret_cast<const float2*>(pos)[d];
    float dx = ps.x - pd.x, dy = ps.y - pd.y;
    float nrm = sqrtf(dx*dx + dy*dy) + EPS;
    float inv = 1.0f / nrm;
    float ux = dx * inv, uy = dy * inv;
    float cdx = fminf(fmaxf(dx, -12.0f), 12.0f);
    float cdy = fminf(fmaxf(dy, -12.0f), 12.0f);
    u64 qdx = (u64)(u32)__float2int_rn((cdx + 12.0f) * 16.0f);
    u64 qdy = (u64)(u32)__float2int_rn((cdy + 12.0f) * 16.0f);
    u64 qux = (u64)(u32)__float2int_rn((ux + 1.0f) * 16.0f);
    u64 quy = (u64)(u32)__float2int_rn((uy + 1.0f) * 16.0f);
    u64 w = qdx | (qdy << 16) | (qux << 32) | (quy << 44) | (1ULL << 56);
    atomicAdd(acc + (size_t)d * 3, w);
}

__global__ void __launch_bounds__(256) node_finalize_kernel(
    const float* __restrict__ pos, float* __restrict__ out)
{
    int i = blockIdx.x * blockDim.x + threadIdx.x;
    if (i >= N_NODES) return;
    u64 w = reinterpret_cast<const u64*>(out)[(size_t)i * 3];
    float cnt = (float)(u32)(w >> 56);
    float sdx = (float)(u32)(w & 0xFFFFULL)         * (1.0f/16.0f) - 12.0f * cnt;
    float sdy = (float)(u32)((w >> 16) & 0xFFFFULL) * (1.0f/16.0f) - 12.0f * cnt;
    float sux = (float)(u32)((w >> 32) & 0xFFFULL)  * (1.0f/16.0f) -  1.0f * cnt;
    float suy = (float)(u32)((w >> 44) & 0xFFFULL)  * (1.0f/16.0f) -  1.0f * cnt;
    float invc = 1.0f / fmaxf(cnt, 1.0f);
    float2 p = reinterpret_cast<const float2*>(pos)[i];
    float* row = out + (size_t)i * 6;
    row[0] = sdx * invc; row[1] = sdy * invc;
    row[2] = sux * invc; row[3] = suy * invc;
    row[4] = p.x; row[5] = p.y;
}

extern "C" void kernel_launch(void* const* d_in, const int* in_sizes, int n_in,
                              void* d_out, int out_size, void* d_ws, size_t ws_size,
                              hipStream_t stream)
{
    const float* pos = (const float*)d_in[0];
    const int* edge_index = (const int*)d_in[1];
    const int* src = edge_index;
    const int* dst = edge_index + N_EDGES;
    float* out = (float*)d_out;

    size_t need_rec    = ((size_t)N_EDGES + 4 * NBINS + 16) * sizeof(u32);      // ~64 MB
    size_t need_counts = (size_t)NBLK_A * NBINS * sizeof(u32);                  // ~2 MB
    size_t need_T      = (size_t)NBINS * sizeof(u32);
    size_t need_S      = (size_t)(NBINS + 1) * sizeof(u32);
    size_t need_Tlen   = (size_t)NBINS * sizeof(u32);
    size_t need_part   = (size_t)NBINS * SPLIT * NODES_PER_BIN * sizeof(u64);   // 32 MB
    size_t need = need_rec + need_counts + need_T + need_S + need_Tlen + need_part + 512;

    if (ws_size < need) {
        // Fallback: single-u64-atomic path (round 3)
        (void)hipMemsetAsync(d_out, 0, (size_t)out_size * sizeof(float), stream);
        int eblocks = (N_EDGES + 255) / 256;
        edge_scatter_kernel<<<eblocks, 256, 0, stream>>>(
            src, dst, pos, reinterpret_cast<u64*>(out));
        int nblocks = (N_NODES + 255) / 256;
        node_finalize_kernel<<<nblocks, 256, 0, stream>>>(pos, out);
        return;
    }

    char* w = (char*)d_ws;
    u32* recbuf  = (u32*)w;           w += need_rec;
    u32* counts  = (u32*)w;           w += need_counts;
    u32* T       = (u32*)w;           w += need_T;
    u32* S       = (u32*)w;           w += need_S;
    u32* Tlen    = (u32*)w;           w += need_Tlen;
    u64* partial = (u64*)w;

    hist_kernel   <<<NBLK_A, 512, 0, stream>>>(dst, counts);
    scanblk_kernel<<<NBINS,  256, 0, stream>>>(counts, T);
    scanbin_kernel<<<1,    NBINS, 0, stream>>>(T, S, Tlen);
    scatter_kernel<<<NBLK_A, 512, 0, stream>>>(src, dst, counts, S, recbuf);
    reduce_kernel <<<NBINS * SPLIT, 512, 0, stream>>>(recbuf, S, Tlen, pos, partial);
    combine_kernel<<<(N_NODES + 511) / 512, 512, 0, stream>>>(partial, pos, out);
}